// Round 5
// baseline (545.636 us; speedup 1.0000x reference)
//
#include <hip/hip_runtime.h>
#include <stdint.h>

// ---------------------------------------------------------------------------
// Bit-level semantics of the reference (row = 64 floats, each exactly 0/1,
// encoding an FP64 bit pattern MSB-first):
//   e      = int(bits 1..11)
//   e_real = (e + 1025) & 0x7FF            // ripple add of -1023, carry dropped
//   is_odd = e_real & 1
//   e_half = (e_real >> 1) | (e_real & 0x400)
//   e_new  = (e_half + 1023) & 0x7FF
//   out    = [0, e_new bits MSB-first, is_odd ? sqrt2_mant bits : 0]
//
// ROUND 4/5 = MEASUREMENT ROUND: kernel unchanged (known-passing).
// kernel_launch issues 3 identical launches (2 into disjoint d_ws halves, 1
// into d_out) to expose the marginal per-launch kernel time:
//   dur_us = overhead + 3*T_k.
// ---------------------------------------------------------------------------

typedef float vf4 __attribute__((ext_vector_type(4)));

constexpr uint64_t SQRT2_MANT = 1865452045155277ULL;  // 52-bit mantissa of sqrt(2)

constexpr uint64_t rev64c(uint64_t x) {
    uint64_t r = 0;
    for (int i = 0; i < 64; ++i) r |= ((x >> i) & 1ULL) << (63 - i);
    return r;
}
constexpr uint64_t SQRT2_REV = rev64c(SQRT2_MANT);  // bit p == SQRT2_MANT bit (63-p)

__global__ __launch_bounds__(256) void SpikeFP64Sqrt_kernel(
    const float* __restrict__ in, vf4* __restrict__ out4, int n4) {
    const int tid    = blockIdx.x * blockDim.x + threadIdx.x;
    const int stride = gridDim.x * blockDim.x;   // multiple of 64
    const int g      = (threadIdx.x & 63) >> 4;  // 16-lane group within wave

    #pragma unroll 4
    for (int c = tid; c < n4; c += stride) {
        const int sub = c & 15;                  // chunk index within the row

        float x = 0.f;
        if (sub < 12) x = in[(size_t)(c >> 4) * 64 + sub];  // 1 dword/lane, 12 lanes/group

        // ballot bit l = row bit for lane l; group g's row occupies bits [16g,16g+15]
        const uint64_t m = __ballot(x != 0.0f);
        const unsigned w = ((unsigned)(m >> (g << 4))) & 0xFFEu;  // bits 1..11 (skip sign)

        unsigned e      = (__brev(w) >> 20) & 0x7FFu;
        unsigned e_real = (e + 1025u) & 0x7FFu;
        unsigned is_odd = e_real & 1u;
        unsigned e_half = (e_real >> 1) | (e_real & 0x400u);
        unsigned e_new  = (e_half + 1023u) & 0x7FFu;

        uint64_t A    = (uint64_t)(__brev(e_new) >> 21);  // A bit q = e_new bit (10-q)
        uint64_t outw = (A << 1) | (SQRT2_REV & (0ULL - (uint64_t)is_odd));

        unsigned bits = (unsigned)(outw >> (sub << 2)) & 0xFu;

        vf4 o;
        o.x = (float)(bits & 1u);
        o.y = (float)((bits >> 1) & 1u);
        o.z = (float)((bits >> 2) & 1u);
        o.w = (float)((bits >> 3) & 1u);
        out4[c] = o;
    }
}

extern "C" void kernel_launch(void* const* d_in, const int* in_sizes, int n_in,
                              void* d_out, int out_size, void* d_ws, size_t ws_size,
                              hipStream_t stream) {
    const float* in   = (const float*)d_in[0];
    vf4*         out4 = (vf4*)d_out;
    const int n4 = out_size / 4;                      // 16,777,216 float4 chunks
    const size_t out_bytes = (size_t)out_size * 4;    // 268 MB

    const int block = 256;
    const int grid  = 2048;                           // 8 blocks/CU, grid-stride x32

    // Two probe launches into disjoint scratch regions (defeat L3 write
    // absorption), then the real one. ws_size is fixed across calls, so the
    // launch sequence is identical every call (graph-capture safe).
    vf4* t0 = (ws_size >= out_bytes)     ? (vf4*)d_ws                          : out4;
    vf4* t1 = (ws_size >= 2 * out_bytes) ? (vf4*)((char*)d_ws + out_bytes)     : out4;
    SpikeFP64Sqrt_kernel<<<grid, block, 0, stream>>>(in, t0, n4);
    SpikeFP64Sqrt_kernel<<<grid, block, 0, stream>>>(in, t1, n4);
    SpikeFP64Sqrt_kernel<<<grid, block, 0, stream>>>(in, out4, n4);
}